// Round 9
// baseline (1083.019 us; speedup 1.0000x reference)
//
#include <hip/hip_runtime.h>
#include <float.h>

// VectorQuantize: h=8 heads, c=2048 codes, d=64, b=8, t=2048 (n=16384 vec/head)
#define H   8
#define C   2048
#define D   64
#define NPH 16384     // vectors per head (b*t)
#define HD  512       // h*d
#define DECAYF 0.9f

// ---------------------------------------------------------------------------
// Kernel 0: e_sq[h,c] = sum_d ke[h,c,d]^2
// ---------------------------------------------------------------------------
__global__ __launch_bounds__(256) void vq_esq_kernel(const float* __restrict__ ke,
                                                     float* __restrict__ esq) {
    int i = blockIdx.x * 256 + threadIdx.x;   // 0 .. H*C-1
    const float* e = ke + (size_t)i * D;
    float s = 0.f;
#pragma unroll
    for (int d = 0; d < D; ++d) s = fmaf(e[d], e[d], s);
    esq[i] = s;
}

// ---------------------------------------------------------------------------
// Kernel 0b: eT[h][k][c] = ke[h][c][k]  (codebook transpose, 4 MB, L2-hot)
// ---------------------------------------------------------------------------
__global__ __launch_bounds__(256) void vq_etr_kernel(const float* __restrict__ ke,
                                                     float* __restrict__ eT) {
    const int b = blockIdx.x;                 // 4096 blocks: h(3b) | k(6b) | cb(3b)
    const int h = b >> 9;
    const int k = (b >> 3) & 63;
    const int c = ((b & 7) << 8) + threadIdx.x;
    eT[((size_t)h << 17) + ((size_t)k << 11) + c] =
        ke[(((size_t)h << 11) + c) * D + k];
}

// ---------------------------------------------------------------------------
// Kernel 1: scalar-pipe distance GEMM + argmin.
//   R9 rationale: R3-R8 all pinned at VALUBusy~32% -- the shared per-CU LDS
//   pipe (4 ds_read_b128 per 64 FMA per wave, x4 SIMDs) is the wall, and the
//   128-VGPR allocator wall blocks bigger register tiles. Fix: make the CODE
//   dimension wave-uniform so e comes from the SCALAR pipe (s_load of eT) and
//   feeds v_fma as the SGPR operand; only x stays on the LDS pipe, read as
//   fully-unique ds_read_b128 (1 instr / 32 FMA -> LDS demand 75%, VALU free).
//   512 blocks x 256 thr: block = head (blk&7) x 256 vectors. 4 waves; wave w
//   scans codes {ch*32 + w*8 + 0..7 : ch=0..63} (ascending per wave). Lane
//   owns vectors lane*4..+3 -> acc[4][8]=32 VGPR. NO barriers in main loop.
//   Score = esq[c] - 2*dot (row-constant dropped, est. R7/R8 passing).
//   fmaf k ascending; first-min + explicit (==, lower idx) cross-wave tie.
// ---------------------------------------------------------------------------
// smem float offsets:
//   sx   [    0, 16384)  x^T [k][v] 64x256  (alive until scatter)
//   rb   [16384, 17408)  per-wave best  [4][256]
//   ri   [17408, 18432)  per-wave bidx  [4][256] (int)
//   sidx [18432, 18688)  final code per vector (int)
#define SMEM_FLOATS 18688

__global__ __launch_bounds__(256, 2)
void vq_main_kernel(const float* __restrict__ x,
                    const float* __restrict__ eT,
                    const float* __restrict__ ke,
                    const float* __restrict__ esq,
                    float* __restrict__ outq,
                    float* __restrict__ outi,
                    float* __restrict__ embsum) {
    __shared__ __align__(16) float smem[SMEM_FLOATS];
    float* sx   = smem;
    float* rb   = smem + 16384;
    int*   ri   = (int*)(smem + 17408);
    int*   sidx = (int*)(smem + 18432);

    const int tid  = threadIdx.x;
    const int lane = tid & 63;
    const int w    = __builtin_amdgcn_readfirstlane(tid >> 6);   // wave id, uniform
    const int h    = blockIdx.x & 7;
    const int vt   = blockIdx.x >> 3;
    const int n0   = vt * 256;          // first vector of this block (within head)

    const float* keh  = ke  + (size_t)h * C * D;
    const float* eTh  = eT  + ((size_t)h << 17);     // [k][c] 64x2048
    const float* esqh = esq + (size_t)h * C;

    // ---- stage x^T: sx[k][v] = x[n0+v][h*64+k]; thread tid stages vector tid
    {
        const float* xp = x + (size_t)(n0 + tid) * HD + (size_t)h * D;
#pragma unroll
        for (int i = 0; i < 16; ++i) {
            float4 wv = ((const float4*)xp)[i];
            sx[(4 * i + 0) * 256 + tid] = wv.x;
            sx[(4 * i + 1) * 256 + tid] = wv.y;
            sx[(4 * i + 2) * 256 + tid] = wv.z;
            sx[(4 * i + 3) * 256 + tid] = wv.w;
        }
    }
    __syncthreads();

    const int vb = lane * 4;            // this lane's 4 vectors (same for all waves)

    float best[4];
    int   bidx[4];
#pragma unroll
    for (int r = 0; r < 4; ++r) { best[r] = FLT_MAX; bidx[r] = 0x7fffffff; }

    // ---- main loop: 64 chunks of 8 wave-uniform codes; no barriers ----
#pragma unroll 1
    for (int ch = 0; ch < 64; ++ch) {
        const int cbase = ch * 32 + w * 8;       // wave-uniform
        const float* ew = eTh + cbase;

        float acc[4][8];
#pragma unroll
        for (int r = 0; r < 4; ++r)
#pragma unroll
            for (int j = 0; j < 8; ++j) acc[r][j] = 0.f;

#pragma unroll 8
        for (int k = 0; k < 64; ++k) {
            float4 xa = *(const float4*)&sx[k * 256 + vb];          // per-lane, unique
            float4 e0 = *(const float4*)(ew + (size_t)k * 2048);    // uniform -> s_load
            float4 e1 = *(const float4*)(ew + (size_t)k * 2048 + 4);
            float xr[4] = {xa.x, xa.y, xa.z, xa.w};
            float ee[8] = {e0.x, e0.y, e0.z, e0.w, e1.x, e1.y, e1.z, e1.w};
#pragma unroll
            for (int r = 0; r < 4; ++r)
#pragma unroll
                for (int j = 0; j < 8; ++j)
                    acc[r][j] = fmaf(xr[r], ee[j], acc[r][j]);
        }

        // epilogue: score = esq[c] - 2*dot ; running first-min (codes ascending)
        float4 q0 = *(const float4*)(esqh + cbase);
        float4 q1 = *(const float4*)(esqh + cbase + 4);
        float eq[8] = {q0.x, q0.y, q0.z, q0.w, q1.x, q1.y, q1.z, q1.w};
#pragma unroll
        for (int r = 0; r < 4; ++r)
#pragma unroll
            for (int j = 0; j < 8; ++j) {
                float sc = fmaf(-2.f, acc[r][j], eq[j]);
                if (sc < best[r]) { best[r] = sc; bidx[r] = cbase + j; }
            }
    }

    // ---- cross-wave argmin reduction ----
#pragma unroll
    for (int r = 0; r < 4; ++r) {
        rb[w * 256 + vb + r] = best[r];
        ri[w * 256 + vb + r] = bidx[r];
    }
    __syncthreads();
    {
        float bb = FLT_MAX;
        int   bi = 0x7fffffff;
#pragma unroll
        for (int g = 0; g < 4; ++g) {
            float b = rb[g * 256 + tid];
            int   i = ri[g * 256 + tid];
            if (b < bb || (b == bb && i < bi)) { bb = b; bi = i; }
        }
        sidx[tid] = bi;
        outi[(size_t)(n0 + tid) * H + h] = (float)bi;   // [b,t,h]
    }
    __syncthreads();

    // ---- gather quantized vectors + scatter-add into emb_sum (2 rounds) ----
#pragma unroll
    for (int ii = 0; ii < 2; ++ii) {
        const int v  = ii * 128 + (tid >> 1);
        const int db = (tid & 1) * 32;
        const int ci = sidx[v];
        const float* ev = keh + (size_t)ci * D + db;
        float* qo = outq + (size_t)(n0 + v) * HD + (size_t)h * D + db;
#pragma unroll
        for (int i = 0; i < 8; ++i)
            ((float4*)qo)[i] = ((const float4*)ev)[i];

        float* es = embsum + ((size_t)h * C + ci) * D + db;
#pragma unroll
        for (int d = 0; d < 32; ++d)
            atomicAdd(es + d, sx[(db + d) * 256 + v]);
    }
}

// ---------------------------------------------------------------------------
// Kernel 2: new_ke = key_optim ? ke + 0.9*(emb_sum - ke) : ke
// ---------------------------------------------------------------------------
__global__ __launch_bounds__(256) void vq_lerp_kernel(const float* __restrict__ ke,
                                                      const float* __restrict__ embsum,
                                                      const int* __restrict__ ko,
                                                      float* __restrict__ outk) {
    int i = (blockIdx.x * 256 + threadIdx.x) * 4;   // H*C*D = 1048576 floats
    const int on = ko[0];
    float4 k4 = *(const float4*)(ke + i);
    float4 s4 = *(const float4*)(embsum + i);
    float4 o4;
    if (on) {
        o4.x = k4.x + DECAYF * (s4.x - k4.x);
        o4.y = k4.y + DECAYF * (s4.y - k4.y);
        o4.z = k4.z + DECAYF * (s4.z - k4.z);
        o4.w = k4.w + DECAYF * (s4.w - k4.w);
    } else {
        o4 = k4;
    }
    *(float4*)(outk + i) = o4;
}

extern "C" void kernel_launch(void* const* d_in, const int* in_sizes, int n_in,
                              void* d_out, int out_size, void* d_ws, size_t ws_size,
                              hipStream_t stream) {
    const float* x  = (const float*)d_in[0];
    const float* ke = (const float*)d_in[1];
    const int*   ko = (const int*)d_in[2];

    float* out  = (float*)d_out;
    float* outq = out;                                   // 8,388,608 floats
    float* outi = out + (size_t)H * NPH * D;             // +131,072 floats
    float* outk = outi + (size_t)NPH * H;                // +1,048,576 floats

    float* embsum = (float*)d_ws;                        // H*C*D = 1,048,576 f32
    float* esq    = embsum + (size_t)H * C * D;          // 16,384 f32
    float* eT     = esq + (size_t)H * C;                 // 1,048,576 f32 (8.45 MB total)

    // zero the scatter accumulator every call (graph-replay safe)
    hipMemsetAsync(embsum, 0, (size_t)H * C * D * sizeof(float), stream);

    vq_esq_kernel<<<(H * C) / 256, 256, 0, stream>>>(ke, esq);
    vq_etr_kernel<<<H * D * (C / 256), 256, 0, stream>>>(ke, eT);
    vq_main_kernel<<<512, 256, 0, stream>>>(x, eT, ke, esq, outq, outi, embsum);
    vq_lerp_kernel<<<(H * C * D) / (256 * 4), 256, 0, stream>>>(ke, embsum, ko, outk);
}

// Round 11
// 905.693 us; speedup vs baseline: 1.1958x; 1.1958x over previous
//
#include <hip/hip_runtime.h>
#include <float.h>

// VectorQuantize: h=8 heads, c=2048 codes, d=64, b=8, t=2048 (n=16384 vec/head)
#define H   8
#define C   2048
#define D   64
#define NPH 16384     // vectors per head (b*t)
#define HD  512       // h*d
#define DECAYF 0.9f
#define DELTA 3.0f    // candidate margin >= 2x worst-case bf16 score error (~0.6)
#define CAP 16        // per-VECTOR candidate slots (R10's per-lane buffer was the bug)

typedef __attribute__((ext_vector_type(8))) short short8v;   // 8 bf16 (4 VGPR)
typedef __attribute__((ext_vector_type(4))) float f32x4;

__device__ inline unsigned short f32_to_bf16_rne(float f) {
    unsigned int x = __float_as_uint(f);
    return (unsigned short)((x + 0x7FFFu + ((x >> 16) & 1u)) >> 16);
}

// ---------------------------------------------------------------------------
// Kernel 0: e_sq[h,c] = sum_d ke[h,c,d]^2
// ---------------------------------------------------------------------------
__global__ __launch_bounds__(256) void vq_esq_kernel(const float* __restrict__ ke,
                                                     float* __restrict__ esq) {
    int i = blockIdx.x * 256 + threadIdx.x;
    const float* e = ke + (size_t)i * D;
    float s = 0.f;
#pragma unroll
    for (int d = 0; d < D; ++d) s = fmaf(e[d], e[d], s);
    esq[i] = s;
}

// ---------------------------------------------------------------------------
// Kernel 0b: keb = bf16(ke)  (RNE; 2 MB, L2-hot)
// ---------------------------------------------------------------------------
__global__ __launch_bounds__(256) void vq_keb_kernel(const float* __restrict__ ke,
                                                     unsigned short* __restrict__ keb) {
    int i = blockIdx.x * 256 + threadIdx.x;   // H*C*D = 1048576
    keb[i] = f32_to_bf16_rne(ke[i]);
}

// ---------------------------------------------------------------------------
// Kernel 1: MFMA screening + exact rescore.
//   Pass 1 (mfma_f32_16x16x32_bf16): per-vec approx min over all 2048 codes.
//   Pass 2: re-run, collect codes with sc <= amin + DELTA into PER-VECTOR
//   LDS lists (ccnt atomicAdd; set is deterministic, order-independent).
//   R10 failure: per-lane evict-worst buffer compared approx scores ACROSS
//   different vectors -> some vecs lost all candidates -> index -1. Fixed.
//   Exact rescore: 1 thread = 1 vec, serial fmaf k-ascending dot, score =
//   fmaf(-2,dot,esq) -- bit-identical chain to passing R7/R8. Lexicographic
//   (score, idx) min => first-min-by-index. ccnt>CAP => deterministic full
//   exact scan fallback (needs >16 codes within DELTA of min; ~impossible).
//   512 blocks x 256 thr: blk&7 = head (XCD L2 affinity), 256 vec/block,
//   wave w owns vecs w*64..+63. A-frags (x bf16) persist in 32 VGPR; B-frags
//   stream from keb global (L2-hot, 256KB/head), depth-1 prefetch; no LDS in
//   the hot loop. Frag layout: lane l: A/B non-K index l&15, k=(l>>4)*8+j
//   (+32 for second frag); C col(code)=lane&15, row(vec)=(lane>>4)*4+reg [m89].
//   (A/B k-slot permutation vs HW cancels: same mapping used for both.)
// ---------------------------------------------------------------------------
__global__ __launch_bounds__(256, 2)
void vq_main_kernel(const float* __restrict__ x,
                    const unsigned short* __restrict__ keb,
                    const float* __restrict__ ke,
                    const float* __restrict__ esq,
                    float* __restrict__ outq,
                    float* __restrict__ outi,
                    float* __restrict__ embsum) {
    __shared__ int            ccnt[256];
    __shared__ unsigned short cand[256][CAP];
    __shared__ int            sidx[256];

    const int tid  = threadIdx.x;
    const int lane = tid & 63;
    const int w    = __builtin_amdgcn_readfirstlane(tid >> 6);
    const int h    = blockIdx.x & 7;
    const int n0   = (blockIdx.x >> 3) * 256;

    const unsigned short* kebh = keb + (size_t)h * C * D;
    const float* keh  = ke  + (size_t)h * C * D;
    const float* esqh = esq + (size_t)h * C;

    ccnt[tid] = 0;
    __syncthreads();

    const int col = lane & 15;        // code col within 16-tile
    const int kg  = (lane >> 4) * 8;  // this lane's k-group base

    // ---- A-frags: lane's 4 vec-rows x 64 k, bf16, persistent in registers ----
    short8v afr[4][2];
#pragma unroll
    for (int vt = 0; vt < 4; ++vt) {
        const float* xp = x + (size_t)(n0 + w * 64 + vt * 16 + col) * HD
                            + (size_t)h * D + kg;
#pragma unroll
        for (int kf = 0; kf < 2; ++kf) {
            float4 u0 = *(const float4*)(xp + kf * 32);
            float4 u1 = *(const float4*)(xp + kf * 32 + 4);
            short8v a;
            a[0] = (short)f32_to_bf16_rne(u0.x); a[1] = (short)f32_to_bf16_rne(u0.y);
            a[2] = (short)f32_to_bf16_rne(u0.z); a[3] = (short)f32_to_bf16_rne(u0.w);
            a[4] = (short)f32_to_bf16_rne(u1.x); a[5] = (short)f32_to_bf16_rne(u1.y);
            a[6] = (short)f32_to_bf16_rne(u1.z); a[7] = (short)f32_to_bf16_rne(u1.w);
            afr[vt][kf] = a;
        }
    }

    float amin[16];
#pragma unroll
    for (int s = 0; s < 16; ++s) amin[s] = FLT_MAX;

#define LOADB16(CB, B0, B1, EQ)                                                \
    {                                                                          \
        const unsigned short* kb = kebh + (size_t)((CB) + col) * D + kg;       \
        B0 = *(const short8v*)(kb);                                            \
        B1 = *(const short8v*)(kb + 32);                                       \
        EQ = esqh[(CB) + col];                                                 \
    }

    // ================= pass 1: per-vector approx min =================
    {
        short8v c0, c1; float q;
        LOADB16(0, c0, c1, q);
#pragma unroll 1
        for (int ch = 0; ch < 128; ++ch) {
            short8v d0, d1; float p;
            const int ncb = ((ch + 1) & 127) << 4;
            LOADB16(ncb, d0, d1, p);
#pragma unroll
            for (int vt = 0; vt < 4; ++vt) {
                f32x4 acc = {0.f, 0.f, 0.f, 0.f};
                acc = __builtin_amdgcn_mfma_f32_16x16x32_bf16(afr[vt][0], c0, acc, 0, 0, 0);
                acc = __builtin_amdgcn_mfma_f32_16x16x32_bf16(afr[vt][1], c1, acc, 0, 0, 0);
#pragma unroll
                for (int r = 0; r < 4; ++r) {
                    float sc = fmaf(-2.f, acc[r], q);
                    amin[vt * 4 + r] = fminf(amin[vt * 4 + r], sc);
                }
            }
            c0 = d0; c1 = d1; q = p;
        }
    }

    // cross-lane min over the 16 lanes sharing (lane>>4)
#pragma unroll
    for (int s = 0; s < 16; ++s) {
        float v = amin[s];
        v = fminf(v, __shfl_xor(v, 1));
        v = fminf(v, __shfl_xor(v, 2));
        v = fminf(v, __shfl_xor(v, 4));
        v = fminf(v, __shfl_xor(v, 8));
        amin[s] = v;
    }

    // ================= pass 2: collect candidates per VECTOR =================
    {
        short8v c0, c1; float q;
        LOADB16(0, c0, c1, q);
#pragma unroll 1
        for (int ch = 0; ch < 128; ++ch) {
            short8v d0, d1; float p;
            const int ncb = ((ch + 1) & 127) << 4;
            LOADB16(ncb, d0, d1, p);
            const int cb = ch << 4;
#pragma unroll
            for (int vt = 0; vt < 4; ++vt) {
                f32x4 acc = {0.f, 0.f, 0.f, 0.f};
                acc = __builtin_amdgcn_mfma_f32_16x16x32_bf16(afr[vt][0], c0, acc, 0, 0, 0);
                acc = __builtin_amdgcn_mfma_f32_16x16x32_bf16(afr[vt][1], c1, acc, 0, 0, 0);
#pragma unroll
                for (int r = 0; r < 4; ++r) {
                    float sc = fmaf(-2.f, acc[r], q);
                    if (sc <= amin[vt * 4 + r] + DELTA) {
                        const int vec = w * 64 + vt * 16 + ((lane >> 4) << 2) + r;
                        int pos = atomicAdd(&ccnt[vec], 1);
                        if (pos < CAP) cand[vec][pos] = (unsigned short)(cb + col);
                    }
                }
            }
            c0 = d0; c1 = d1; q = p;
        }
    }
    __syncthreads();

    // ================= exact f32 rescore: thread tid <-> vec tid =================
    {
        const float4* xr = (const float4*)(x + (size_t)(n0 + tid) * HD + (size_t)h * D);
        const int nc = ccnt[tid];
        float bb = FLT_MAX;
        int   bi = 0x7fffffff;
        if (nc <= CAP) {
            for (int i = 0; i < nc; ++i) {
                const int code = cand[tid][i];
                const float4* er = (const float4*)(keh + (size_t)code * D);
                float s = 0.f;
#pragma unroll 4
                for (int kq = 0; kq < 16; ++kq) {
                    float4 a4 = xr[kq]; float4 e4 = er[kq];
                    s = fmaf(a4.x, e4.x, s); s = fmaf(a4.y, e4.y, s);
                    s = fmaf(a4.z, e4.z, s); s = fmaf(a4.w, e4.w, s);
                }
                float sc = fmaf(-2.f, s, esqh[code]);
                if (sc < bb || (sc == bb && code < bi)) { bb = sc; bi = code; }
            }
        } else {
            // deterministic fallback: full exact scan, ascending => first-min
            for (int code = 0; code < C; ++code) {
                const float4* er = (const float4*)(keh + (size_t)code * D);
                float s = 0.f;
#pragma unroll 4
                for (int kq = 0; kq < 16; ++kq) {
                    float4 a4 = xr[kq]; float4 e4 = er[kq];
                    s = fmaf(a4.x, e4.x, s); s = fmaf(a4.y, e4.y, s);
                    s = fmaf(a4.z, e4.z, s); s = fmaf(a4.w, e4.w, s);
                }
                float sc = fmaf(-2.f, s, esqh[code]);
                if (sc < bb) { bb = sc; bi = code; }
            }
        }
        sidx[tid] = bi;
        outi[(size_t)(n0 + tid) * H + h] = (float)bi;   // [b,t,h]
    }
    __syncthreads();

    // ---- gather quantized vectors + scatter-add into emb_sum ----
#pragma unroll
    for (int ii = 0; ii < 2; ++ii) {
        const int v  = ii * 128 + (tid >> 1);
        const int db = (tid & 1) * 32;
        const int ci = sidx[v];
        const float* ev = keh + (size_t)ci * D + db;
        float* qo = outq + (size_t)(n0 + v) * HD + (size_t)h * D + db;
#pragma unroll
        for (int i = 0; i < 8; ++i)
            ((float4*)qo)[i] = ((const float4*)ev)[i];

        const float* xs = x + (size_t)(n0 + v) * HD + (size_t)h * D + db;
        float* es = embsum + ((size_t)h * C + ci) * D + db;
#pragma unroll
        for (int i = 0; i < 8; ++i) {
            float4 xv = ((const float4*)xs)[i];
            atomicAdd(es + 4 * i + 0, xv.x);
            atomicAdd(es + 4 * i + 1, xv.y);
            atomicAdd(es + 4 * i + 2, xv.z);
            atomicAdd(es + 4 * i + 3, xv.w);
        }
    }
}

// ---------------------------------------------------------------------------
// Kernel 2: new_ke = key_optim ? ke + 0.9*(emb_sum - ke) : ke
// ---------------------------------------------------------------------------
__global__ __launch_bounds__(256) void vq_lerp_kernel(const float* __restrict__ ke,
                                                      const float* __restrict__ embsum,
                                                      const int* __restrict__ ko,
                                                      float* __restrict__ outk) {
    int i = (blockIdx.x * 256 + threadIdx.x) * 4;   // H*C*D = 1048576 floats
    const int on = ko[0];
    float4 k4 = *(const float4*)(ke + i);
    float4 s4 = *(const float4*)(embsum + i);
    float4 o4;
    if (on) {
        o4.x = k4.x + DECAYF * (s4.x - k4.x);
        o4.y = k4.y + DECAYF * (s4.y - k4.y);
        o4.z = k4.z + DECAYF * (s4.z - k4.z);
        o4.w = k4.w + DECAYF * (s4.w - k4.w);
    } else {
        o4 = k4;
    }
    *(float4*)(outk + i) = o4;
}

extern "C" void kernel_launch(void* const* d_in, const int* in_sizes, int n_in,
                              void* d_out, int out_size, void* d_ws, size_t ws_size,
                              hipStream_t stream) {
    const float* x  = (const float*)d_in[0];
    const float* ke = (const float*)d_in[1];
    const int*   ko = (const int*)d_in[2];

    float* out  = (float*)d_out;
    float* outq = out;                                   // 8,388,608 floats
    float* outi = out + (size_t)H * NPH * D;             // +131,072 floats
    float* outk = outi + (size_t)NPH * H;                // +1,048,576 floats

    float* embsum = (float*)d_ws;                        // H*C*D f32 (4 MB)
    float* esq    = embsum + (size_t)H * C * D;          // 16,384 f32
    unsigned short* keb = (unsigned short*)(esq + (size_t)H * C);  // 1M bf16 (2 MB)

    // zero the scatter accumulator every call (graph-replay safe)
    hipMemsetAsync(embsum, 0, (size_t)H * C * D * sizeof(float), stream);

    vq_esq_kernel<<<(H * C) / 256, 256, 0, stream>>>(ke, esq);
    vq_keb_kernel<<<(H * C * D) / 256, 256, 0, stream>>>(ke, keb);
    vq_main_kernel<<<512, 256, 0, stream>>>(x, keb, ke, esq, outq, outi, embsum);
    vq_lerp_kernel<<<(H * C * D) / (256 * 4), 256, 0, stream>>>(ke, embsum, ko, outk);
}

// Round 12
// 392.563 us; speedup vs baseline: 2.7588x; 2.3071x over previous
//
#include <hip/hip_runtime.h>
#include <float.h>

// VectorQuantize: h=8 heads, c=2048 codes, d=64, b=8, t=2048 (n=16384 vec/head)
#define H   8
#define C   2048
#define D   64
#define NPH 16384     // vectors per head (b*t)
#define HD  512       // h*d
#define DECAYF 0.9f
#define DELTA 3.0f    // candidate margin >= 2x worst-case bf16 score error (~0.6)
#define CAP 64        // per-vector candidate slots (also pads LDS to ~35KB ->
                      // allocator targets 4 blocks/CU -> 128-VGPR budget)

typedef __attribute__((ext_vector_type(8))) short short8v;   // 8 bf16 (4 VGPR)
typedef __attribute__((ext_vector_type(4))) float f32x4;

__device__ inline unsigned short f32_to_bf16_rne(float f) {
    unsigned int x = __float_as_uint(f);
    return (unsigned short)((x + 0x7FFFu + ((x >> 16) & 1u)) >> 16);
}

// ---------------------------------------------------------------------------
// Kernel 0: e_sq[h,c] = sum_d ke[h,c,d]^2
// ---------------------------------------------------------------------------
__global__ __launch_bounds__(256) void vq_esq_kernel(const float* __restrict__ ke,
                                                     float* __restrict__ esq) {
    int i = blockIdx.x * 256 + threadIdx.x;
    const float* e = ke + (size_t)i * D;
    float s = 0.f;
#pragma unroll
    for (int d = 0; d < D; ++d) s = fmaf(e[d], e[d], s);
    esq[i] = s;
}

// ---------------------------------------------------------------------------
// Kernel 0b: keb = bf16(ke)
// ---------------------------------------------------------------------------
__global__ __launch_bounds__(256) void vq_keb_kernel(const float* __restrict__ ke,
                                                     unsigned short* __restrict__ keb) {
    int i = blockIdx.x * 256 + threadIdx.x;   // H*C*D = 1048576
    keb[i] = f32_to_bf16_rne(ke[i]);
}

// ---------------------------------------------------------------------------
// Kernel 1: MFMA screening + exact rescore (R11 structure, PASSED; atomic
//   scatter tail removed -- session finding: 8.4M device-scope atomicAdds
//   wrote ~268MB through to HBM at ~11G atomics/s = the 820-950us floor of
//   EVERY round since R3. emb_sum now computed by K2-K5 sort+reduce.)
//   Writes: outi (f32), indw (u16 per-head code ids), outq (gather).
// ---------------------------------------------------------------------------
__global__ __launch_bounds__(256, 2)
void vq_main_kernel(const float* __restrict__ x,
                    const unsigned short* __restrict__ keb,
                    const float* __restrict__ ke,
                    const float* __restrict__ esq,
                    float* __restrict__ outq,
                    float* __restrict__ outi,
                    unsigned short* __restrict__ indw) {
    __shared__ int            ccnt[256];
    __shared__ unsigned short cand[256][CAP];
    __shared__ int            sidx[256];

    const int tid  = threadIdx.x;
    const int lane = tid & 63;
    const int w    = __builtin_amdgcn_readfirstlane(tid >> 6);
    const int h    = blockIdx.x & 7;
    const int n0   = (blockIdx.x >> 3) * 256;

    const unsigned short* kebh = keb + (size_t)h * C * D;
    const float* keh  = ke  + (size_t)h * C * D;
    const float* esqh = esq + (size_t)h * C;

    ccnt[tid] = 0;
    __syncthreads();

    const int col = lane & 15;        // code col within 16-tile
    const int kg  = (lane >> 4) * 8;  // this lane's k-group base

    // ---- A-frags: lane's 4 vec-rows x 64 k, bf16, persistent ----
    short8v afr[4][2];
#pragma unroll
    for (int vt = 0; vt < 4; ++vt) {
        const float* xp = x + (size_t)(n0 + w * 64 + vt * 16 + col) * HD
                            + (size_t)h * D + kg;
#pragma unroll
        for (int kf = 0; kf < 2; ++kf) {
            float4 u0 = *(const float4*)(xp + kf * 32);
            float4 u1 = *(const float4*)(xp + kf * 32 + 4);
            short8v a;
            a[0] = (short)f32_to_bf16_rne(u0.x); a[1] = (short)f32_to_bf16_rne(u0.y);
            a[2] = (short)f32_to_bf16_rne(u0.z); a[3] = (short)f32_to_bf16_rne(u0.w);
            a[4] = (short)f32_to_bf16_rne(u1.x); a[5] = (short)f32_to_bf16_rne(u1.y);
            a[6] = (short)f32_to_bf16_rne(u1.z); a[7] = (short)f32_to_bf16_rne(u1.w);
            afr[vt][kf] = a;
        }
    }

    float amin[16];
#pragma unroll
    for (int s = 0; s < 16; ++s) amin[s] = FLT_MAX;

#define LOADB16(CB, B0, B1, EQ)                                                \
    {                                                                          \
        const unsigned short* kb = kebh + (size_t)((CB) + col) * D + kg;       \
        B0 = *(const short8v*)(kb);                                            \
        B1 = *(const short8v*)(kb + 32);                                       \
        EQ = esqh[(CB) + col];                                                 \
    }

    // ================= pass 1: per-vector approx min =================
    {
        short8v c0, c1; float q;
        LOADB16(0, c0, c1, q);
#pragma unroll 1
        for (int ch = 0; ch < 128; ++ch) {
            short8v d0, d1; float p;
            const int ncb = ((ch + 1) & 127) << 4;
            LOADB16(ncb, d0, d1, p);
#pragma unroll
            for (int vt = 0; vt < 4; ++vt) {
                f32x4 acc = {0.f, 0.f, 0.f, 0.f};
                acc = __builtin_amdgcn_mfma_f32_16x16x32_bf16(afr[vt][0], c0, acc, 0, 0, 0);
                acc = __builtin_amdgcn_mfma_f32_16x16x32_bf16(afr[vt][1], c1, acc, 0, 0, 0);
#pragma unroll
                for (int r = 0; r < 4; ++r) {
                    float sc = fmaf(-2.f, acc[r], q);
                    amin[vt * 4 + r] = fminf(amin[vt * 4 + r], sc);
                }
            }
            c0 = d0; c1 = d1; q = p;
        }
    }

    // cross-lane min over the 16 lanes sharing (lane>>4)
#pragma unroll
    for (int s = 0; s < 16; ++s) {
        float v = amin[s];
        v = fminf(v, __shfl_xor(v, 1));
        v = fminf(v, __shfl_xor(v, 2));
        v = fminf(v, __shfl_xor(v, 4));
        v = fminf(v, __shfl_xor(v, 8));
        amin[s] = v;
    }

    // ================= pass 2: collect candidates per VECTOR =================
    {
        short8v c0, c1; float q;
        LOADB16(0, c0, c1, q);
#pragma unroll 1
        for (int ch = 0; ch < 128; ++ch) {
            short8v d0, d1; float p;
            const int ncb = ((ch + 1) & 127) << 4;
            LOADB16(ncb, d0, d1, p);
            const int cb = ch << 4;
#pragma unroll
            for (int vt = 0; vt < 4; ++vt) {
                f32x4 acc = {0.f, 0.f, 0.f, 0.f};
                acc = __builtin_amdgcn_mfma_f32_16x16x32_bf16(afr[vt][0], c0, acc, 0, 0, 0);
                acc = __builtin_amdgcn_mfma_f32_16x16x32_bf16(afr[vt][1], c1, acc, 0, 0, 0);
#pragma unroll
                for (int r = 0; r < 4; ++r) {
                    float sc = fmaf(-2.f, acc[r], q);
                    if (sc <= amin[vt * 4 + r] + DELTA) {
                        const int vec = w * 64 + vt * 16 + ((lane >> 4) << 2) + r;
                        int pos = atomicAdd(&ccnt[vec], 1);
                        if (pos < CAP) cand[vec][pos] = (unsigned short)(cb + col);
                    }
                }
            }
            c0 = d0; c1 = d1; q = p;
        }
    }
    __syncthreads();

    // ================= exact f32 rescore: thread tid <-> vec tid =================
    {
        const float4* xr = (const float4*)(x + (size_t)(n0 + tid) * HD + (size_t)h * D);
        const int nc = ccnt[tid];
        float bb = FLT_MAX;
        int   bi = 0x7fffffff;
        if (nc <= CAP) {
            for (int i = 0; i < nc; ++i) {
                const int code = cand[tid][i];
                const float4* er = (const float4*)(keh + (size_t)code * D);
                float s = 0.f;
#pragma unroll 4
                for (int kq = 0; kq < 16; ++kq) {
                    float4 a4 = xr[kq]; float4 e4 = er[kq];
                    s = fmaf(a4.x, e4.x, s); s = fmaf(a4.y, e4.y, s);
                    s = fmaf(a4.z, e4.z, s); s = fmaf(a4.w, e4.w, s);
                }
                float sc = fmaf(-2.f, s, esqh[code]);
                if (sc < bb || (sc == bb && code < bi)) { bb = sc; bi = code; }
            }
        } else {
            // deterministic fallback: full exact scan, ascending => first-min
            for (int code = 0; code < C; ++code) {
                const float4* er = (const float4*)(keh + (size_t)code * D);
                float s = 0.f;
#pragma unroll 4
                for (int kq = 0; kq < 16; ++kq) {
                    float4 a4 = xr[kq]; float4 e4 = er[kq];
                    s = fmaf(a4.x, e4.x, s); s = fmaf(a4.y, e4.y, s);
                    s = fmaf(a4.z, e4.z, s); s = fmaf(a4.w, e4.w, s);
                }
                float sc = fmaf(-2.f, s, esqh[code]);
                if (sc < bb) { bb = sc; bi = code; }
            }
        }
        sidx[tid] = bi;
        outi[(size_t)(n0 + tid) * H + h] = (float)bi;          // [b,t,h]
        indw[((size_t)h << 14) + n0 + tid] = (unsigned short)bi;
    }
    __syncthreads();

    // ---- gather quantized vectors (no atomics) ----
#pragma unroll
    for (int ii = 0; ii < 2; ++ii) {
        const int v  = ii * 128 + (tid >> 1);
        const int db = (tid & 1) * 32;
        const int ci = sidx[v];
        const float* ev = keh + (size_t)ci * D + db;
        float* qo = outq + (size_t)(n0 + v) * HD + (size_t)h * D + db;
#pragma unroll
        for (int i = 0; i < 8; ++i)
            ((float4*)qo)[i] = ((const float4*)ev)[i];
    }
}

// ---------------------------------------------------------------------------
// Kernel 2: per-block LDS histogram of codes -> global counts (u32[8][2048])
// ---------------------------------------------------------------------------
__global__ __launch_bounds__(256) void vq_hist_kernel(const unsigned short* __restrict__ ind,
                                                      unsigned int* __restrict__ counts) {
    __shared__ unsigned int hist[C];
    const int tid = threadIdx.x;
    const int h   = blockIdx.x >> 3;
    const int sub = blockIdx.x & 7;
#pragma unroll
    for (int j = 0; j < 8; ++j) hist[j * 256 + tid] = 0;
    __syncthreads();
    const unsigned short* p = ind + ((size_t)h << 14) + (sub << 11);
#pragma unroll
    for (int j = 0; j < 8; ++j)
        atomicAdd(&hist[p[j * 256 + tid]], 1u);
    __syncthreads();
#pragma unroll
    for (int j = 0; j < 8; ++j) {
        const int c = j * 256 + tid;
        const unsigned int v = hist[c];
        if (v) atomicAdd(&counts[(h << 11) + c], v);
    }
}

// ---------------------------------------------------------------------------
// Kernel 3: per-head exclusive prefix scan of counts -> off, cur
// ---------------------------------------------------------------------------
__global__ __launch_bounds__(256) void vq_scan_kernel(const unsigned int* __restrict__ counts,
                                                      unsigned int* __restrict__ off,
                                                      unsigned int* __restrict__ cur) {
    __shared__ unsigned int sa[C], sb[C];
    const int h   = blockIdx.x;
    const int tid = threadIdx.x;
#pragma unroll
    for (int j = 0; j < 8; ++j) sa[j * 256 + tid] = counts[(h << 11) + j * 256 + tid];
    __syncthreads();
    unsigned int* src = sa;
    unsigned int* dst = sb;
    for (int s = 1; s < C; s <<= 1) {
#pragma unroll
        for (int j = 0; j < 8; ++j) {
            const int c = j * 256 + tid;
            unsigned int v = src[c];
            if (c >= s) v += src[c - s];
            dst[c] = v;
        }
        __syncthreads();
        unsigned int* t = src; src = dst; dst = t;
    }
#pragma unroll
    for (int j = 0; j < 8; ++j) {
        const int c = j * 256 + tid;
        const unsigned int e = c ? src[c - 1] : 0u;
        off[(h << 11) + c] = e;
        cur[(h << 11) + c] = e;
    }
}

// ---------------------------------------------------------------------------
// Kernel 4: scatter vec-ids into per-code lists (131K cursor atomics)
// ---------------------------------------------------------------------------
__global__ __launch_bounds__(256) void vq_scatter_kernel(const unsigned short* __restrict__ ind,
                                                         unsigned int* __restrict__ cur,
                                                         unsigned short* __restrict__ perm) {
    const int g = blockIdx.x * 256 + threadIdx.x;   // 131072
    const int h = g >> 14;
    const int n = g & 16383;
    const int c = ind[g];
    const unsigned int pos = atomicAdd(&cur[(h << 11) + c], 1u);
    perm[((size_t)h << 14) + pos] = (unsigned short)n;
}

// ---------------------------------------------------------------------------
// Kernel 5: segmented reduce + fused EMA lerp. One wave per (head,code);
//   lane = d. f64 accumulation => order-independent to far below threshold.
//   Plain coalesced stores -- zero atomics.
// ---------------------------------------------------------------------------
__global__ __launch_bounds__(256) void vq_reduce_kernel(const float* __restrict__ x,
                                                        const float* __restrict__ ke,
                                                        const unsigned short* __restrict__ perm,
                                                        const unsigned int* __restrict__ counts,
                                                        const unsigned int* __restrict__ off,
                                                        const int* __restrict__ ko,
                                                        float* __restrict__ outk) {
    const int tid  = threadIdx.x;
    const int lane = tid & 63;
    const int pair = blockIdx.x * 4 + (tid >> 6);   // == h*2048 + c
    const int h    = pair >> 11;

    const unsigned int cnt = counts[pair];
    const unsigned int o   = off[pair];
    const unsigned short* pl = perm + ((size_t)h << 14) + o;

    double acc = 0.0;
    for (unsigned int i = 0; i < cnt; ++i) {
        const int vid = pl[i];   // wave-uniform broadcast load
        acc += (double)x[(size_t)vid * HD + (size_t)h * D + lane];
    }
    const float esum = (float)acc;
    const float kv   = ke[(size_t)pair * D + lane];
    const float ov   = ko[0] ? (kv + DECAYF * (esum - kv)) : kv;
    outk[(size_t)pair * D + lane] = ov;
}

extern "C" void kernel_launch(void* const* d_in, const int* in_sizes, int n_in,
                              void* d_out, int out_size, void* d_ws, size_t ws_size,
                              hipStream_t stream) {
    const float* x  = (const float*)d_in[0];
    const float* ke = (const float*)d_in[1];
    const int*   ko = (const int*)d_in[2];

    float* out  = (float*)d_out;
    float* outq = out;                                   // 8,388,608 floats
    float* outi = out + (size_t)H * NPH * D;             // +131,072 floats
    float* outk = outi + (size_t)NPH * H;                // +1,048,576 floats

    // workspace layout
    float*          esq    = (float*)d_ws;                              // 16,384 f32
    unsigned short* keb    = (unsigned short*)(esq + H * C);            // 1M u16
    unsigned short* indw   = keb + (size_t)H * C * D;                   // 131,072 u16
    unsigned int*   counts = (unsigned int*)(indw + (size_t)H * NPH);   // 16,384 u32
    unsigned int*   offv   = counts + H * C;                            // 16,384 u32
    unsigned int*   curv   = offv + H * C;                              // 16,384 u32
    unsigned short* perm   = (unsigned short*)(curv + H * C);           // 131,072 u16

    hipMemsetAsync(counts, 0, (size_t)H * C * sizeof(unsigned int), stream);

    vq_esq_kernel<<<(H * C) / 256, 256, 0, stream>>>(ke, esq);
    vq_keb_kernel<<<(H * C * D) / 256, 256, 0, stream>>>(ke, keb);
    vq_main_kernel<<<512, 256, 0, stream>>>(x, keb, ke, esq, outq, outi, indw);
    vq_hist_kernel<<<64, 256, 0, stream>>>(indw, counts);
    vq_scan_kernel<<<H, 256, 0, stream>>>(counts, offv, curv);
    vq_scatter_kernel<<<512, 256, 0, stream>>>(indw, curv, perm);
    vq_reduce_kernel<<<(H * C) / 4, 256, 0, stream>>>(x, ke, perm, counts, offv, ko, outk);
}